// Round 2
// baseline (775.762 us; speedup 1.0000x reference)
//
#include <hip/hip_runtime.h>
#include <cstdint>

// LeNet-5 forward, B=16384, fp32. 5 kernels:
//   k_mask  : mw3 = w3 * connection_mask          (ws)
//   k_front : x -> C1+S2 fused -> C3(+S4) -> s4 (B,400)
//   k_c5    : s4 @ w5^T + b5, tanh -> h5T (120,B)
//   k_f6    : h5T @ f6w^T + f6b, tanh -> h6T (84,B)
//   k_rbf   : squared distance to rbf bitmaps -> out (B,10)

#define A_SCALE 1.7159f

// A*tanh(S*v), S=2/3.  tanh(y) = 1 - 2/(exp(2y)+1); 2*S*v = (4/3)v.
__device__ __forceinline__ float tact(float v) {
    float e = __expf(1.33333333f * v);
    float r = __builtin_amdgcn_rcpf(e + 1.0f);
    return A_SCALE * (1.0f - 2.0f * r);
}

__device__ const int C3MASK[16] = {0x07,0x0E,0x1C,0x38,0x31,0x23,0x0F,0x1E,
                                   0x3C,0x39,0x33,0x27,0x1B,0x36,0x2D,0x3F};

__global__ __launch_bounds__(256) void k_mask(const float* __restrict__ w3,
                                              float* __restrict__ mw3) {
    int i = blockIdx.x * 256 + threadIdx.x;
    if (i < 2400) {
        int oc = i / 150;
        int ic = (i % 150) / 25;
        mw3[i] = w3[i] * (float)((C3MASK[oc] >> ic) & 1);
    }
}

// ---------------- front: C1 + S2 + C3 + S4 (8 samples per block) -------------
__global__ __launch_bounds__(256) void k_front(
    const float* __restrict__ x,
    const float* __restrict__ w1, const float* __restrict__ b1,
    const float* __restrict__ s2w, const float* __restrict__ s2b,
    const float* __restrict__ mw3, const float* __restrict__ b3,
    const float* __restrict__ s4w, const float* __restrict__ s4b,
    float* __restrict__ s4o)
{
    __shared__ __align__(16) float u0[8192];    // x [8][1024]; later c3 slice [8][4][100]
    __shared__ __align__(16) float s2p[10752];  // [8][6][14][16]  (row padded 14->16)
    const int t = threadIdx.x;
    const int b0 = blockIdx.x * 8;

    { // stage x: 8*1024 floats as float4
        const float4* xg = (const float4*)(x + (size_t)b0 * 1024);
        float4* xs = (float4*)u0;
        #pragma unroll
        for (int i = 0; i < 8; ++i) xs[t + 256 * i] = xg[t + 256 * i];
    }
    __syncthreads();

    // ---- C1 (5x5, 1->6) fused with S2 pooling (quad = 4 consecutive in-row) ----
    // task: (ch uniform outer) x (sm, oy-pair, qx): computes 2x4 conv outputs,
    // tanh each, pools each row-quad -> 2 s2 outputs.
    for (int ch = 0; ch < 6; ++ch) {
        float wr[25];
        #pragma unroll
        for (int k = 0; k < 25; ++k) wr[k] = w1[ch * 25 + k];  // uniform -> s_load
        const float bb = b1[ch], sw = s2w[ch], sbv = s2b[ch];
        for (int i = t; i < 784; i += 256) {     // 8 sm * 98
            const int sm = i / 98;
            const int j  = i % 98;               // 14 oy-pairs * 7 qx
            const int oy = (j / 7) * 2;
            const int qx = j % 7;
            const float* xp = u0 + sm * 1024 + oy * 32 + qx * 4;
            float o0[4], o1[4];
            #pragma unroll
            for (int d = 0; d < 4; ++d) { o0[d] = bb; o1[d] = bb; }
            #pragma unroll
            for (int r = 0; r < 6; ++r) {        // 6-row window covers both out rows
                float4 va = *(const float4*)(xp + r * 32);
                float4 vb = *(const float4*)(xp + r * 32 + 4);
                float xr[8] = {va.x, va.y, va.z, va.w, vb.x, vb.y, vb.z, vb.w};
                if (r < 5) {
                    #pragma unroll
                    for (int kx = 0; kx < 5; ++kx) {
                        float w = wr[r * 5 + kx];
                        #pragma unroll
                        for (int d = 0; d < 4; ++d) o0[d] += xr[kx + d] * w;
                    }
                }
                if (r >= 1) {
                    #pragma unroll
                    for (int kx = 0; kx < 5; ++kx) {
                        float w = wr[(r - 1) * 5 + kx];
                        #pragma unroll
                        for (int d = 0; d < 4; ++d) o1[d] += xr[kx + d] * w;
                    }
                }
            }
            float m0 = 0.25f * (tact(o0[0]) + tact(o0[1]) + tact(o0[2]) + tact(o0[3]));
            float m1 = 0.25f * (tact(o1[0]) + tact(o1[1]) + tact(o1[2]) + tact(o1[3]));
            float v0 = tact(m0 * sw + sbv);
            float v1 = tact(m1 * sw + sbv);
            int k0 = oy * 7 + qx;                // flat-quad index == s2 flat index
            int k1 = k0 + 7;
            s2p[sm * 1344 + ch * 224 + (k0 / 14) * 16 + (k0 % 14)] = v0;
            s2p[sm * 1344 + ch * 224 + (k1 / 14) * 16 + (k1 % 14)] = v1;
        }
    }
    __syncthreads();

    // ---- C3 (dense masked 6->16) in 4 uniform oc-quad passes, then S4 ----
    float* c3s = u0;   // x buffer is dead; reuse as [8][4][100] slice
    for (int g = 0; g < 4; ++g) {
        if (t < 240) {
            const int sm = t / 30;
            const int j  = t % 30;               // oy(10) x qx3(3)
            const int oy = j / 3;
            const int ox0 = (j % 3) * 4;
            float acc[4][4];
            #pragma unroll
            for (int a = 0; a < 4; ++a) {
                float bv = b3[g * 4 + a];        // uniform -> s_load
                #pragma unroll
                for (int d = 0; d < 4; ++d) acc[a][d] = bv;
            }
            const float* sp = s2p + sm * 1344;
            #pragma unroll
            for (int ic = 0; ic < 6; ++ic) {
                const float* ip = sp + ic * 224 + oy * 16 + ox0;
                #pragma unroll
                for (int ky = 0; ky < 5; ++ky) {
                    float4 va = *(const float4*)(ip + ky * 16);
                    float4 vb = *(const float4*)(ip + ky * 16 + 4);
                    float xr[8] = {va.x, va.y, va.z, va.w, vb.x, vb.y, vb.z, vb.w};
                    #pragma unroll
                    for (int a = 0; a < 4; ++a) {
                        const float* wp = mw3 + ((g * 4 + a) * 6 + ic) * 25 + ky * 5; // uniform -> s_load
                        #pragma unroll
                        for (int kx = 0; kx < 5; ++kx) {
                            float w = wp[kx];
                            #pragma unroll
                            for (int d = 0; d < 4; ++d) acc[a][d] += xr[kx + d] * w;
                        }
                    }
                }
            }
            #pragma unroll
            for (int a = 0; a < 4; ++a) {
                #pragma unroll
                for (int d = 0; d < 4; ++d) {
                    int ox = ox0 + d;
                    if (ox < 10)                // ox0==8 tile: only dx 0,1 valid
                        c3s[sm * 400 + a * 100 + oy * 10 + ox] = tact(acc[a][d]);
                }
            }
        }
        __syncthreads();
        // S4 pooling for this oc-quad: flat quads of the (10,10) map
        for (int i = t; i < 800; i += 256) {     // 8 sm * 4 a * 25 q
            int sm = i / 100;
            int rest = i % 100;
            int a = rest / 25;
            int q = rest % 25;
            int oc = g * 4 + a;
            float4 v = *(const float4*)(c3s + sm * 400 + a * 100 + q * 4);
            float m = 0.25f * (v.x + v.y + v.z + v.w);
            s4o[(size_t)(b0 + sm) * 400 + oc * 25 + q] = tact(m * s4w[oc] + s4b[oc]);
        }
        __syncthreads();
    }
}

// ---------------- C5: (B,400) x (400,120)^T, 64 samples/block ----------------
__global__ __launch_bounds__(256) void k_c5(
    const float* __restrict__ s4, const float* __restrict__ w5,
    const float* __restrict__ b5, float* __restrict__ h5T)
{
    __shared__ __align__(16) float sA[6800];    // transposed chunk [k(100)][68]
    __shared__ __align__(16) float sW[12400];   // transposed chunk [k(100)][124]
    const int t = threadIdx.x;
    const int cg = t % 30;                      // channels cg*4 .. cg*4+3
    const int smg = (t / 30 < 8) ? (t / 30) : 7;// samples smg*8 .. smg*8+7
    const int b64 = blockIdx.x * 64;

    float acc[8][4];
    #pragma unroll
    for (int u = 0; u < 8; ++u)
        #pragma unroll
        for (int v = 0; v < 4; ++v) acc[u][v] = 0.0f;

    for (int kc = 0; kc < 4; ++kc) {
        __syncthreads();
        for (int i = t; i < 6400; i += 256) {   // A chunk, coalesced read, transposed store
            int s = i / 100, k = i % 100;
            sA[k * 68 + s] = s4[(size_t)(b64 + s) * 400 + kc * 100 + k];
        }
        for (int i = t; i < 12000; i += 256) {  // W chunk (L1-friendly strided read)
            int k = i / 120, ch = i % 120;
            sW[k * 124 + ch] = w5[(size_t)ch * 400 + kc * 100 + k];
        }
        __syncthreads();
        for (int k = 0; k < 100; ++k) {
            const float* ap = sA + k * 68 + smg * 8;
            float4 a0 = *(const float4*)(ap);
            float4 a1 = *(const float4*)(ap + 4);
            float4 w  = *(const float4*)(sW + k * 124 + cg * 4);
            float av[8] = {a0.x, a0.y, a0.z, a0.w, a1.x, a1.y, a1.z, a1.w};
            float wv[4] = {w.x, w.y, w.z, w.w};
            #pragma unroll
            for (int u = 0; u < 8; ++u)
                #pragma unroll
                for (int v = 0; v < 4; ++v) acc[u][v] += av[u] * wv[v];
        }
    }
    if (t < 240) {
        float4 bv = *(const float4*)(b5 + cg * 4);
        float bb[4] = {bv.x, bv.y, bv.z, bv.w};
        #pragma unroll
        for (int v = 0; v < 4; ++v) {
            int ch = cg * 4 + v;
            #pragma unroll
            for (int u = 0; u < 8; ++u)
                h5T[(size_t)ch * 16384 + b64 + smg * 8 + u] = tact(acc[u][v] + bb[v]);
        }
    }
}

// ---------------- F6: sample-per-lane GEMV, weights in SGPRs -----------------
__global__ __launch_bounds__(256) void k_f6(
    const float* __restrict__ h5T, const float* __restrict__ f6w,
    const float* __restrict__ f6b, float* __restrict__ h6T)
{
    const int t = threadIdx.x;
    const int sb = blockIdx.x & 63;
    const int og = blockIdx.x >> 6;             // 0..3 -> 21 outputs each
    const int s = sb * 256 + t;
    float acc[21];
    #pragma unroll
    for (int o = 0; o < 21; ++o) acc[o] = f6b[og * 21 + o];
    for (int kc = 0; kc < 5; ++kc) {
        float a[24];
        #pragma unroll
        for (int j = 0; j < 24; ++j) a[j] = h5T[(size_t)(kc * 24 + j) * 16384 + s];
        #pragma unroll
        for (int o = 0; o < 21; ++o) {
            const float* wp = f6w + (size_t)(og * 21 + o) * 120 + kc * 24; // uniform -> s_load
            #pragma unroll
            for (int j = 0; j < 24; ++j) acc[o] += a[j] * wp[j];
        }
    }
    #pragma unroll
    for (int o = 0; o < 21; ++o)
        h6T[(size_t)(og * 21 + o) * 16384 + s] = tact(acc[o]);
}

// ---------------- RBF head ---------------------------------------------------
__global__ __launch_bounds__(256) void k_rbf(
    const float* __restrict__ h6T, const float* __restrict__ rbf,
    float* __restrict__ out)
{
    const int s = blockIdx.x * 256 + threadIdx.x;
    float acc[10];
    #pragma unroll
    for (int c = 0; c < 10; ++c) acc[c] = 0.0f;
    for (int j = 0; j < 84; ++j) {
        float a = h6T[(size_t)j * 16384 + s];
        #pragma unroll
        for (int c = 0; c < 10; ++c) {
            float d = a - rbf[c * 84 + j];      // uniform -> s_load
            acc[c] += d * d;
        }
    }
    #pragma unroll
    for (int c = 0; c < 10; ++c) out[(size_t)s * 10 + c] = acc[c];
}

extern "C" void kernel_launch(void* const* d_in, const int* in_sizes, int n_in,
                              void* d_out, int out_size, void* d_ws, size_t ws_size,
                              hipStream_t stream)
{
    const float* x    = (const float*)d_in[0];
    const float* w1   = (const float*)d_in[1];
    const float* b1   = (const float*)d_in[2];
    const float* s2w  = (const float*)d_in[3];
    const float* s2b  = (const float*)d_in[4];
    const float* w3   = (const float*)d_in[5];
    const float* b3   = (const float*)d_in[6];
    const float* s4w  = (const float*)d_in[7];
    const float* s4b  = (const float*)d_in[8];
    const float* w5   = (const float*)d_in[9];
    const float* b5   = (const float*)d_in[10];
    const float* f6w  = (const float*)d_in[11];
    const float* f6b  = (const float*)d_in[12];
    const float* rbfw = (const float*)d_in[13];
    float* out = (float*)d_out;
    float* ws  = (float*)d_ws;

    float* mw3 = ws;                            // 2400 floats
    float* s4  = ws + 4096;                     // 16384*400
    float* h5T = s4 + 16384 * 400;              // 120*16384
    float* h6T = h5T + 120 * 16384;             // 84*16384  (total ~39.6 MB)

    k_mask <<<10,   256, 0, stream>>>(w3, mw3);
    k_front<<<2048, 256, 0, stream>>>(x, w1, b1, s2w, s2b, mw3, b3, s4w, s4b, s4);
    k_c5   <<<256,  256, 0, stream>>>(s4, w5, b5, h5T);
    k_f6   <<<256,  256, 0, stream>>>(h5T, f6w, f6b, h6T);
    k_rbf  <<<64,   256, 0, stream>>>(h6T, rbfw, out);
}

// Round 5
// 578.046 us; speedup vs baseline: 1.3420x; 1.3420x over previous
//
#include <hip/hip_runtime.h>
#include <cstdint>

// LeNet-5 forward, B=16384. Batch-lane design: lane = sample, wave-uniform
// control, [feature][B] layouts, f32 FMA math, f16 pair-packed storage.
// R5: 2 chunks of 8192 samples -> peak workspace 36.0 MB (ws proven >= 39.6 MB;
// R4's 72 MB overran ws and corrupted the harness's pristine input copies).
// Pair-packed u32 loads halve VMEM instruction count vs R4.
//
// Per-chunk workspace (byte offsets, peak 36,044,800 B):
//   XP  u32 [512][NC] @ 0           (16,777,216)  x f16 col-pairs; dead after k_c1s2
//   S2P u32 [588][NC] @ 16,777,216  (19,267,584)  s2 (col p, col p+7) pairs; dead after k_c3s4
//   S4  f32 [400][NC] @ 0           (13,107,200)  overlaps dead XP
//   H5P u32 [ 60][NC] @ 13,107,200  ( 1,966,080)  h5 pairs, overlaps dead XP tail
//   H6  f32 [ 84][NC] @ 16,777,216  ( 2,752,512)  overlaps dead S2P

typedef unsigned int u32;
#define NC 8192

union U32H2 { u32 u; _Float16 h[2]; };
__device__ __forceinline__ float f16lo(u32 v) { U32H2 a; a.u = v; return (float)a.h[0]; }
__device__ __forceinline__ float f16hi(u32 v) { U32H2 a; a.u = v; return (float)a.h[1]; }
__device__ __forceinline__ u32 packh2(float a, float b) {
    U32H2 x; x.h[0] = (_Float16)a; x.h[1] = (_Float16)b; return x.u;
}

// A*tanh(S*v), S=2/3: tanh(y) = 1 - 2/(exp(2y)+1), 2y = (4/3)v
__device__ __forceinline__ float tact(float v) {
    float e = __expf(1.3333333333f * v);
    return 1.7159f * (1.0f - 2.0f * __builtin_amdgcn_rcpf(e + 1.0f));
}

// C3 sparse connection lists (from reference CONNECTIONS)
__device__ const int C3_NIC[16] = {3,3,3,3,3,3, 4,4,4,4,4,4,4,4,4, 6};
__device__ const int C3_ICL[96] = {
    0,1,2,0,0,0,  1,2,3,0,0,0,  2,3,4,0,0,0,  3,4,5,0,0,0,
    0,4,5,0,0,0,  0,1,5,0,0,0,  0,1,2,3,0,0,  1,2,3,4,0,0,
    2,3,4,5,0,0,  0,3,4,5,0,0,  0,1,4,5,0,0,  0,1,2,5,0,0,
    0,1,3,4,0,0,  1,2,4,5,0,0,  0,2,3,5,0,0,  0,1,2,3,4,5 };

// ---------------- transpose: x chunk (NC,1024) f32 -> xp u32[512][NC] -------
// xp[(r*16+j)][sl] = (x[r][2j], x[r][2j+1]) as f16 pair.
__global__ __launch_bounds__(256) void k_tr(const float* __restrict__ x,
                                            u32* __restrict__ xp)
{
    __shared__ _Float16 lds[64 * 66];
    const int t = threadIdx.x;
    const int tb = blockIdx.x * 64;          // sample tile
    const int tp = blockIdx.y * 64;          // position tile
    #pragma unroll
    for (int i = 0; i < 16; ++i) {           // coalesced read along positions
        int idx = i * 256 + t;
        int bl = idx >> 6, pl = idx & 63;
        lds[pl * 66 + bl] = (_Float16)x[(size_t)(tb + bl) * 1024 + tp + pl];
    }
    __syncthreads();
    #pragma unroll
    for (int j = 0; j < 8; ++j) {            // coalesced pair-write along batch
        int idx = j * 256 + t;
        int pp = idx >> 6, bl = idx & 63;    // pp in [0,32)
        U32H2 u;
        u.h[0] = lds[(2 * pp) * 66 + bl];
        u.h[1] = lds[(2 * pp + 1) * 66 + bl];
        xp[(size_t)(blockIdx.y * 32 + pp) * NC + tb + bl] = u.u;
    }
}

// ---------------- C1 + S2 fused, grid (NC/256, 14) --------------------------
// blockIdx.y = s2 row oy2. Sliding u32-pair window, f32 FMA.
// S2P pair layout: s2p[(ch*98 + row*7 + p)][sl] = (s2[row][p], s2[row][p+7]).
__global__ __launch_bounds__(256) void k_c1s2(
    const u32* __restrict__ xp,
    const float* __restrict__ w1, const float* __restrict__ b1,
    const float* __restrict__ s2w, const float* __restrict__ s2b,
    u32* __restrict__ s2p)
{
    const int sl = blockIdx.x * 256 + threadIdx.x;
    const int oy2 = blockIdx.y;
    const int y0 = 2 * oy2;
    const u32* xb = xp + sl;

    u32 cur[6][4];                           // pairs 2qx..2qx+3, rows y0..y0+5
    #pragma unroll
    for (int r = 0; r < 6; ++r)
        #pragma unroll
        for (int c = 0; c < 4; ++c)
            cur[r][c] = xb[(size_t)((y0 + r) * 16 + c) * NC];

    for (int qx = 0; qx < 7; ++qx) {
        float xw[6][8];                      // unpacked window cols 4qx..4qx+7
        #pragma unroll
        for (int r = 0; r < 6; ++r)
            #pragma unroll
            for (int c = 0; c < 4; ++c) {
                xw[r][2 * c]     = f16lo(cur[r][c]);
                xw[r][2 * c + 1] = f16hi(cur[r][c]);
            }

        #pragma unroll
        for (int ch = 0; ch < 6; ++ch) {
            const float* wp = w1 + ch * 25;  // uniform -> s_load
            const float bb = b1[ch];
            float o[2][4];
            #pragma unroll
            for (int u = 0; u < 2; ++u)
                #pragma unroll
                for (int d = 0; d < 4; ++d) o[u][d] = bb;
            #pragma unroll
            for (int u = 0; u < 2; ++u)
                #pragma unroll
                for (int ky = 0; ky < 5; ++ky)
                    #pragma unroll
                    for (int kx = 0; kx < 5; ++kx) {
                        const float w = wp[ky * 5 + kx];
                        #pragma unroll
                        for (int d = 0; d < 4; ++d)
                            o[u][d] += xw[u + ky][kx + d] * w;
                    }
            const float sw = s2w[ch], sb = s2b[ch];
            // pool_affine reshape: s2[oy2][qx]   = mean conv[2oy2  ][4qx..4qx+3]
            //                      s2[oy2][qx+7] = mean conv[2oy2+1][4qx..4qx+3]
            float m0 = 0.25f * (tact(o[0][0]) + tact(o[0][1]) + tact(o[0][2]) + tact(o[0][3]));
            float m1 = 0.25f * (tact(o[1][0]) + tact(o[1][1]) + tact(o[1][2]) + tact(o[1][3]));
            s2p[(size_t)(ch * 98 + oy2 * 7 + qx) * NC + sl] =
                packh2(tact(sw * m0 + sb), tact(sw * m1 + sb));
        }

        if (qx < 6) {                        // slide window: +2 new pairs/row
            #pragma unroll
            for (int r = 0; r < 6; ++r) {
                cur[r][0] = cur[r][2];
                cur[r][1] = cur[r][3];
                cur[r][2] = xb[(size_t)((y0 + r) * 16 + 2 * qx + 4) * NC];
                cur[r][3] = xb[(size_t)((y0 + r) * 16 + 2 * qx + 5) * NC];
            }
        }
    }
}

// ---------------- C3 + S4 fused, grid (NC/256, 16) --------------------------
// blockIdx.y = oc. Row pairs (2y2, 2y2+1) so reshape-flat S4 quads form in regs.
__global__ __launch_bounds__(256) void k_c3s4(
    const u32* __restrict__ s2p, const float* __restrict__ w3,
    const float* __restrict__ b3, const float* __restrict__ s4w,
    const float* __restrict__ s4b, float* __restrict__ s4)
{
    const int sl = blockIdx.x * 256 + threadIdx.x;
    const int oc = blockIdx.y;
    const int nic = C3_NIC[oc];
    const float bb = b3[oc], swv = s4w[oc], sbv = s4b[oc];

    for (int y2 = 0; y2 < 5; ++y2) {
        float a2[2][10];
        #pragma unroll
        for (int u = 0; u < 2; ++u)
            #pragma unroll
            for (int ox = 0; ox < 10; ++ox) a2[u][ox] = bb;

        for (int e = 0; e < nic; ++e) {      // uniform sparse plane loop
            const int ic = C3_ICL[oc * 6 + e];
            const u32* sp = s2p + (size_t)(ic * 98 + 2 * y2 * 7) * NC + sl;
            float win[6][14];                // input rows 2y2..2y2+5
            #pragma unroll
            for (int r = 0; r < 6; ++r)
                #pragma unroll
                for (int p = 0; p < 7; ++p) {
                    const u32 v = sp[(size_t)(r * 7 + p) * NC];
                    win[r][p]     = f16lo(v);
                    win[r][p + 7] = f16hi(v);
                }
            const float* wp = w3 + (oc * 6 + ic) * 25;  // uniform -> s_load
            #pragma unroll
            for (int u = 0; u < 2; ++u)
                #pragma unroll
                for (int ky = 0; ky < 5; ++ky)
                    #pragma unroll
                    for (int kx = 0; kx < 5; ++kx) {
                        const float w = wp[ky * 5 + kx];
                        #pragma unroll
                        for (int ox = 0; ox < 10; ++ox)
                            a2[u][ox] += win[u + ky][kx + ox] * w;
                    }
        }
        // tanh, then S4 reshape-flat pooling over local flat f = u*10+ox
        float tv[20];
        #pragma unroll
        for (int u = 0; u < 2; ++u)
            #pragma unroll
            for (int ox = 0; ox < 10; ++ox) tv[u * 10 + ox] = tact(a2[u][ox]);
        #pragma unroll
        for (int x2 = 0; x2 < 5; ++x2) {
            float m = 0.25f * (tv[x2 * 4] + tv[x2 * 4 + 1] + tv[x2 * 4 + 2] + tv[x2 * 4 + 3]);
            s4[(size_t)(oc * 25 + y2 * 5 + x2) * NC + sl] = tact(m * swv + sbv);
        }
    }
}

// ---------------- C5: 120-ch GEMV over flat 400, grid (NC/256, 12) ----------
__global__ __launch_bounds__(256) void k_c5(
    const float* __restrict__ s4, const float* __restrict__ w5,
    const float* __restrict__ b5, u32* __restrict__ h5p)
{
    const int sl = blockIdx.x * 256 + threadIdx.x;
    const int chg = blockIdx.y;              // channels chg*10 .. chg*10+9
    float acc[10];
    #pragma unroll
    for (int c = 0; c < 10; ++c) acc[c] = b5[chg * 10 + c];
    #pragma unroll 4
    for (int i = 0; i < 400; ++i) {
        const float v = s4[(size_t)i * NC + sl];
        #pragma unroll
        for (int c = 0; c < 10; ++c)
            acc[c] += v * w5[(size_t)(chg * 10 + c) * 400 + i];  // uniform -> s_load
    }
    #pragma unroll
    for (int j = 0; j < 5; ++j)
        h5p[(size_t)(chg * 5 + j) * NC + sl] =
            packh2(tact(acc[2 * j]), tact(acc[2 * j + 1]));
}

// ---------------- F6: 84-out GEMV over 60 h5 pairs, grid (NC/256, 6) --------
__global__ __launch_bounds__(256) void k_f6(
    const u32* __restrict__ h5p, const float* __restrict__ f6w,
    const float* __restrict__ f6b, float* __restrict__ h6)
{
    const int sl = blockIdx.x * 256 + threadIdx.x;
    const int og = blockIdx.y;               // outputs og*14 .. og*14+13
    float hv[120];
    #pragma unroll
    for (int i = 0; i < 60; ++i) {
        const u32 v = h5p[(size_t)i * NC + sl];
        hv[2 * i]     = f16lo(v);
        hv[2 * i + 1] = f16hi(v);
    }
    float acc[14];
    #pragma unroll
    for (int o = 0; o < 14; ++o) acc[o] = f6b[og * 14 + o];
    #pragma unroll 4
    for (int i = 0; i < 120; ++i) {
        #pragma unroll
        for (int o = 0; o < 14; ++o)
            acc[o] += hv[i] * f6w[(size_t)(og * 14 + o) * 120 + i];  // uniform
    }
    #pragma unroll
    for (int o = 0; o < 14; ++o)
        h6[(size_t)(og * 14 + o) * NC + sl] = tact(acc[o]);
}

// ---------------- RBF head, grid (NC/256) -----------------------------------
__global__ __launch_bounds__(256) void k_rbf(
    const float* __restrict__ h6, const float* __restrict__ rbf,
    float* __restrict__ out)
{
    const int sl = blockIdx.x * 256 + threadIdx.x;
    float hv[84];
    #pragma unroll 4
    for (int i = 0; i < 84; ++i) hv[i] = h6[(size_t)i * NC + sl];
    #pragma unroll
    for (int c = 0; c < 10; ++c) {
        float acc = 0.0f;
        #pragma unroll 4
        for (int i = 0; i < 84; ++i) {
            float d = hv[i] - rbf[c * 84 + i];   // uniform -> s_load
            acc += d * d;
        }
        out[(size_t)sl * 10 + c] = acc;
    }
}

extern "C" void kernel_launch(void* const* d_in, const int* in_sizes, int n_in,
                              void* d_out, int out_size, void* d_ws, size_t ws_size,
                              hipStream_t stream)
{
    const float* x    = (const float*)d_in[0];
    const float* w1   = (const float*)d_in[1];
    const float* b1   = (const float*)d_in[2];
    const float* s2w  = (const float*)d_in[3];
    const float* s2b  = (const float*)d_in[4];
    const float* w3   = (const float*)d_in[5];
    const float* b3   = (const float*)d_in[6];
    const float* s4w  = (const float*)d_in[7];
    const float* s4b  = (const float*)d_in[8];
    const float* w5   = (const float*)d_in[9];
    const float* b5   = (const float*)d_in[10];
    const float* f6w  = (const float*)d_in[11];
    const float* f6b  = (const float*)d_in[12];
    const float* rbfw = (const float*)d_in[13];
    char* ws = (char*)d_ws;

    u32*  XP  = (u32*)(ws);                  // 16,777,216 B
    float* S4 = (float*)(ws);                // 13,107,200 B (XP dead)
    u32*  H5P = (u32*)(ws + 13107200);       //  1,966,080 B (XP dead)
    u32*  S2P = (u32*)(ws + 16777216);       // 19,267,584 B
    float* H6 = (float*)(ws + 16777216);     //  2,752,512 B (S2P dead)

    for (int c = 0; c < 2; ++c) {
        const float* xc = x + (size_t)c * NC * 1024;
        float* outc = (float*)d_out + (size_t)c * NC * 10;
        k_tr  <<<dim3(NC / 64, 16), 256, 0, stream>>>(xc, XP);
        k_c1s2<<<dim3(NC / 256, 14), 256, 0, stream>>>(XP, w1, b1, s2w, s2b, S2P);
        k_c3s4<<<dim3(NC / 256, 16), 256, 0, stream>>>(S2P, w3, b3, s4w, s4b, S4);
        k_c5  <<<dim3(NC / 256, 12), 256, 0, stream>>>(S4, w5, b5, H5P);
        k_f6  <<<dim3(NC / 256, 6), 256, 0, stream>>>(H5P, f6w, f6b, H6);
        k_rbf <<<NC / 256, 256, 0, stream>>>(H6, rbfw, outc);
    }
}

// Round 6
// 408.133 us; speedup vs baseline: 1.9008x; 1.4163x over previous
//
#include <hip/hip_runtime.h>
#include <cstdint>

// LeNet-5 forward, B=16384. Batch-lane design: lane = sample, wave-uniform
// control, [feature][N] layouts, f32 FMA math, f16 pair-packed storage.
// R6: fine-grained grids (c3s4 split by (oc,y2); c1s2 by (oy2,chpair); rbf by
// class-pair) + adaptive plan on ws_size:
//   Plan A (ws >= 55,312,384 B): S2P full-batch; front in 2 chunks of 8192;
//     tail kernels single launch at N=16384. 8 dispatches.
//     layout: S2P u32[588][16384] @ 0                    (38,535,168)
//             XP  u32[512][ 8192] @ 38,535,168           (16,777,216) front only
//             S4H f16[400][16384] @ 38,535,168           (13,107,200) after front
//             H5P u32[ 60][16384] @ 0                    ( 3,932,160) after c3s4
//             H6P u32[ 42][16384] @ 4,194,304            ( 2,752,512)
//   Plan B (else): R5-proven per-chunk layout, peak 36,044,800 B. 12 dispatches.
//     per chunk (N=8192): XP @0 (16,777,216), S2P @16,777,216 (19,267,584),
//             S4H f16 @0 (6,553,600), H5P @6,553,600, H6P @8,519,680.

typedef unsigned int u32;

union U32H2 { u32 u; _Float16 h[2]; };
__device__ __forceinline__ float f16lo(u32 v) { U32H2 a; a.u = v; return (float)a.h[0]; }
__device__ __forceinline__ float f16hi(u32 v) { U32H2 a; a.u = v; return (float)a.h[1]; }
__device__ __forceinline__ u32 packh2(float a, float b) {
    U32H2 x; x.h[0] = (_Float16)a; x.h[1] = (_Float16)b; return x.u;
}

// A*tanh(S*v), S=2/3: tanh(y) = 1 - 2/(exp(2y)+1), 2y = (4/3)v
__device__ __forceinline__ float tact(float v) {
    float e = __expf(1.3333333333f * v);
    return 1.7159f * (1.0f - 2.0f * __builtin_amdgcn_rcpf(e + 1.0f));
}

// C3 sparse connection lists (from reference CONNECTIONS)
__device__ const int C3_NIC[16] = {3,3,3,3,3,3, 4,4,4,4,4,4,4,4,4, 6};
__device__ const int C3_ICL[96] = {
    0,1,2,0,0,0,  1,2,3,0,0,0,  2,3,4,0,0,0,  3,4,5,0,0,0,
    0,4,5,0,0,0,  0,1,5,0,0,0,  0,1,2,3,0,0,  1,2,3,4,0,0,
    2,3,4,5,0,0,  0,3,4,5,0,0,  0,1,4,5,0,0,  0,1,2,5,0,0,
    0,1,3,4,0,0,  1,2,4,5,0,0,  0,2,3,5,0,0,  0,1,2,3,4,5 };

// ---------------- transpose: x chunk (8192,1024) f32 -> xp u32[512][8192] ---
// xp[r*16+j][sl] = (x[r][2j], x[r][2j+1]) f16 pair. grid (128, 16).
__global__ __launch_bounds__(256) void k_tr(const float* __restrict__ x,
                                            u32* __restrict__ xp)
{
    __shared__ _Float16 lds[64 * 66];
    const int t = threadIdx.x;
    const int tb = blockIdx.x * 64;          // sample tile
    const int tp = blockIdx.y * 64;          // position tile
    #pragma unroll
    for (int i = 0; i < 16; ++i) {           // coalesced read along positions
        int idx = i * 256 + t;
        int bl = idx >> 6, pl = idx & 63;
        lds[pl * 66 + bl] = (_Float16)x[(size_t)(tb + bl) * 1024 + tp + pl];
    }
    __syncthreads();
    #pragma unroll
    for (int j = 0; j < 8; ++j) {            // coalesced pair-write along batch
        int idx = j * 256 + t;
        int pp = idx >> 6, bl = idx & 63;    // pp in [0,32)
        U32H2 u;
        u.h[0] = lds[(2 * pp) * 66 + bl];
        u.h[1] = lds[(2 * pp + 1) * 66 + bl];
        xp[(size_t)(blockIdx.y * 32 + pp) * 8192 + tb + bl] = u.u;
    }
}

// ---------------- C1 + S2 fused, grid (32, 42) ------------------------------
// blockIdx.y = oy2*3 + chpair. xp stride fixed 8192 (chunk); s2p stride ostr,
// chunk column offset folded into s2p pointer.
// S2P pair layout: s2p[(ch*98 + oy2*7 + qx)*ostr + sl] = (s2[oy2][qx], s2[oy2][qx+7]).
__global__ __launch_bounds__(256) void k_c1s2(
    const u32* __restrict__ xp,
    const float* __restrict__ w1, const float* __restrict__ b1,
    const float* __restrict__ s2w, const float* __restrict__ s2b,
    u32* __restrict__ s2p, int ostr)
{
    const int sl = blockIdx.x * 256 + threadIdx.x;
    const int oy2 = blockIdx.y / 3;
    const int cp  = blockIdx.y % 3;          // channels 2cp, 2cp+1
    const int y0 = 2 * oy2;
    const u32* xb = xp + sl;

    u32 cur[6][4];                           // pairs 2qx..2qx+3, rows y0..y0+5
    #pragma unroll
    for (int r = 0; r < 6; ++r)
        #pragma unroll
        for (int c = 0; c < 4; ++c)
            cur[r][c] = xb[(size_t)((y0 + r) * 16 + c) * 8192];

    for (int qx = 0; qx < 7; ++qx) {
        float xw[6][8];                      // unpacked window cols 4qx..4qx+7
        #pragma unroll
        for (int r = 0; r < 6; ++r)
            #pragma unroll
            for (int c = 0; c < 4; ++c) {
                xw[r][2 * c]     = f16lo(cur[r][c]);
                xw[r][2 * c + 1] = f16hi(cur[r][c]);
            }

        #pragma unroll
        for (int a = 0; a < 2; ++a) {
            const int ch = 2 * cp + a;
            const float* wp = w1 + ch * 25;  // uniform -> s_load
            const float bb = b1[ch];
            float o[2][4];
            #pragma unroll
            for (int u = 0; u < 2; ++u)
                #pragma unroll
                for (int d = 0; d < 4; ++d) o[u][d] = bb;
            #pragma unroll
            for (int u = 0; u < 2; ++u)
                #pragma unroll
                for (int ky = 0; ky < 5; ++ky)
                    #pragma unroll
                    for (int kx = 0; kx < 5; ++kx) {
                        const float w = wp[ky * 5 + kx];
                        #pragma unroll
                        for (int d = 0; d < 4; ++d)
                            o[u][d] += xw[u + ky][kx + d] * w;
                    }
            const float sw = s2w[ch], sb = s2b[ch];
            // pool_affine reshape: s2[oy2][qx]   = mean conv[2oy2  ][4qx..4qx+3]
            //                      s2[oy2][qx+7] = mean conv[2oy2+1][4qx..4qx+3]
            float m0 = 0.25f * (tact(o[0][0]) + tact(o[0][1]) + tact(o[0][2]) + tact(o[0][3]));
            float m1 = 0.25f * (tact(o[1][0]) + tact(o[1][1]) + tact(o[1][2]) + tact(o[1][3]));
            s2p[(size_t)(ch * 98 + oy2 * 7 + qx) * ostr + sl] =
                packh2(tact(sw * m0 + sb), tact(sw * m1 + sb));
        }

        if (qx < 6) {                        // slide window: +2 new pairs/row
            #pragma unroll
            for (int r = 0; r < 6; ++r) {
                cur[r][0] = cur[r][2];
                cur[r][1] = cur[r][3];
                cur[r][2] = xb[(size_t)((y0 + r) * 16 + 2 * qx + 4) * 8192];
                cur[r][3] = xb[(size_t)((y0 + r) * 16 + 2 * qx + 5) * 8192];
            }
        }
    }
}

// ---------------- C3 + S4 fused, grid (nb/256, 80) --------------------------
// blockIdx.y = oc*5 + y2. One c3 row-pair -> tanh -> one s4 row (f16).
__global__ __launch_bounds__(256) void k_c3s4(
    const u32* __restrict__ s2p, const float* __restrict__ w3,
    const float* __restrict__ b3, const float* __restrict__ s4w,
    const float* __restrict__ s4b, _Float16* __restrict__ s4h, int nb)
{
    const int sl = blockIdx.x * 256 + threadIdx.x;
    const int oc = blockIdx.y / 5;
    const int y2 = blockIdx.y % 5;
    const int nic = C3_NIC[oc];
    const float bb = b3[oc];

    float a2[2][10];
    #pragma unroll
    for (int u = 0; u < 2; ++u)
        #pragma unroll
        for (int ox = 0; ox < 10; ++ox) a2[u][ox] = bb;

    for (int e = 0; e < nic; ++e) {          // uniform sparse plane loop
        const int ic = C3_ICL[oc * 6 + e];
        const u32* sp = s2p + (size_t)(ic * 98 + 2 * y2 * 7) * nb + sl;
        float win[6][14];                    // s2 rows 2y2..2y2+5
        #pragma unroll
        for (int r = 0; r < 6; ++r)
            #pragma unroll
            for (int p = 0; p < 7; ++p) {
                const u32 v = sp[(size_t)(r * 7 + p) * nb];
                win[r][p]     = f16lo(v);
                win[r][p + 7] = f16hi(v);
            }
        const float* wp = w3 + (oc * 6 + ic) * 25;  // uniform -> s_load
        #pragma unroll
        for (int u = 0; u < 2; ++u)
            #pragma unroll
            for (int ky = 0; ky < 5; ++ky)
                #pragma unroll
                for (int kx = 0; kx < 5; ++kx) {
                    const float w = wp[ky * 5 + kx];
                    #pragma unroll
                    for (int ox = 0; ox < 10; ++ox)
                        a2[u][ox] += win[u + ky][kx + ox] * w;
                }
    }
    // tanh, then S4 reshape-flat pooling over local flat f = u*10+ox
    float tv[20];
    #pragma unroll
    for (int u = 0; u < 2; ++u)
        #pragma unroll
        for (int ox = 0; ox < 10; ++ox) tv[u * 10 + ox] = tact(a2[u][ox]);
    const float swv = s4w[oc], sbv = s4b[oc];
    #pragma unroll
    for (int x2 = 0; x2 < 5; ++x2) {
        float m = 0.25f * (tv[x2 * 4] + tv[x2 * 4 + 1] + tv[x2 * 4 + 2] + tv[x2 * 4 + 3]);
        s4h[(size_t)(oc * 25 + y2 * 5 + x2) * nb + sl] = (_Float16)tact(m * swv + sbv);
    }
}

// ---------------- C5: 120-ch GEMV over flat 400, grid (nb/256, 12) ----------
__global__ __launch_bounds__(256) void k_c5(
    const _Float16* __restrict__ s4h, const float* __restrict__ w5,
    const float* __restrict__ b5, u32* __restrict__ h5p, int nb)
{
    const int sl = blockIdx.x * 256 + threadIdx.x;
    const int chg = blockIdx.y;              // channels chg*10 .. chg*10+9
    float acc[10];
    #pragma unroll
    for (int c = 0; c < 10; ++c) acc[c] = b5[chg * 10 + c];
    #pragma unroll 4
    for (int i = 0; i < 400; ++i) {
        const float v = (float)s4h[(size_t)i * nb + sl];
        #pragma unroll
        for (int c = 0; c < 10; ++c)
            acc[c] += v * w5[(size_t)(chg * 10 + c) * 400 + i];  // uniform -> s_load
    }
    #pragma unroll
    for (int j = 0; j < 5; ++j)
        h5p[(size_t)(chg * 5 + j) * nb + sl] =
            packh2(tact(acc[2 * j]), tact(acc[2 * j + 1]));
}

// ---------------- F6: 84-out GEMV over 60 h5 pairs, grid (nb/256, 6) --------
__global__ __launch_bounds__(256) void k_f6(
    const u32* __restrict__ h5p, const float* __restrict__ f6w,
    const float* __restrict__ f6b, u32* __restrict__ h6p, int nb)
{
    const int sl = blockIdx.x * 256 + threadIdx.x;
    const int og = blockIdx.y;               // outputs og*14 .. og*14+13
    float hv[120];
    #pragma unroll
    for (int i = 0; i < 60; ++i) {
        const u32 v = h5p[(size_t)i * nb + sl];
        hv[2 * i]     = f16lo(v);
        hv[2 * i + 1] = f16hi(v);
    }
    float acc[14];
    #pragma unroll
    for (int o = 0; o < 14; ++o) acc[o] = f6b[og * 14 + o];
    #pragma unroll 4
    for (int i = 0; i < 120; ++i) {
        #pragma unroll
        for (int o = 0; o < 14; ++o)
            acc[o] += hv[i] * f6w[(size_t)(og * 14 + o) * 120 + i];  // uniform
    }
    #pragma unroll
    for (int j = 0; j < 7; ++j)
        h6p[(size_t)(og * 7 + j) * nb + sl] =
            packh2(tact(acc[2 * j]), tact(acc[2 * j + 1]));
}

// ---------------- RBF head, grid (nb/256, 5): 2 classes per block -----------
__global__ __launch_bounds__(256) void k_rbf(
    const u32* __restrict__ h6p, const float* __restrict__ rbf,
    float* __restrict__ out, int nb)
{
    const int sl = blockIdx.x * 256 + threadIdx.x;
    const int gy = blockIdx.y;
    float hv[84];
    #pragma unroll
    for (int i = 0; i < 42; ++i) {
        const u32 v = h6p[(size_t)i * nb + sl];
        hv[2 * i]     = f16lo(v);
        hv[2 * i + 1] = f16hi(v);
    }
    #pragma unroll
    for (int a = 0; a < 2; ++a) {
        const int c = 2 * gy + a;
        float acc = 0.0f;
        #pragma unroll 4
        for (int i = 0; i < 84; ++i) {
            float d = hv[i] - rbf[c * 84 + i];   // uniform -> s_load
            acc += d * d;
        }
        out[(size_t)sl * 10 + c] = acc;
    }
}

extern "C" void kernel_launch(void* const* d_in, const int* in_sizes, int n_in,
                              void* d_out, int out_size, void* d_ws, size_t ws_size,
                              hipStream_t stream)
{
    const float* x    = (const float*)d_in[0];
    const float* w1   = (const float*)d_in[1];
    const float* b1   = (const float*)d_in[2];
    const float* s2w  = (const float*)d_in[3];
    const float* s2b  = (const float*)d_in[4];
    const float* w3   = (const float*)d_in[5];
    const float* b3   = (const float*)d_in[6];
    const float* s4w  = (const float*)d_in[7];
    const float* s4b  = (const float*)d_in[8];
    const float* w5   = (const float*)d_in[9];
    const float* b5   = (const float*)d_in[10];
    const float* f6w  = (const float*)d_in[11];
    const float* f6b  = (const float*)d_in[12];
    const float* rbfw = (const float*)d_in[13];
    float* out = (float*)d_out;
    char* ws = (char*)d_ws;

    if (ws_size >= 55312384) {
        // ---- Plan A: full-batch tail (8 dispatches) ----
        u32*      S2P = (u32*)(ws);                       // 38,535,168 B
        u32*      XP  = (u32*)(ws + 38535168);            // 16,777,216 B (front)
        _Float16* S4H = (_Float16*)(ws + 38535168);       // 13,107,200 B (after front)
        u32*      H5P = (u32*)(ws);                       //  3,932,160 B (after c3s4)
        u32*      H6P = (u32*)(ws + 4194304);             //  2,752,512 B
        for (int c = 0; c < 2; ++c) {
            k_tr  <<<dim3(128, 16), 256, 0, stream>>>(x + (size_t)c * 8192 * 1024, XP);
            k_c1s2<<<dim3(32, 42), 256, 0, stream>>>(XP, w1, b1, s2w, s2b,
                                                     S2P + (size_t)c * 8192, 16384);
        }
        k_c3s4<<<dim3(64, 80), 256, 0, stream>>>(S2P, w3, b3, s4w, s4b, S4H, 16384);
        k_c5  <<<dim3(64, 12), 256, 0, stream>>>(S4H, w5, b5, H5P, 16384);
        k_f6  <<<dim3(64, 6), 256, 0, stream>>>(H5P, f6w, f6b, H6P, 16384);
        k_rbf <<<dim3(64, 5), 256, 0, stream>>>(H6P, rbfw, out, 16384);
    } else {
        // ---- Plan B: 2 chunks, R5-proven 36.0 MB layout (12 dispatches) ----
        u32*      XP  = (u32*)(ws);                       // 16,777,216 B
        u32*      S2P = (u32*)(ws + 16777216);            // 19,267,584 B
        _Float16* S4H = (_Float16*)(ws);                  //  6,553,600 B (XP dead)
        u32*      H5P = (u32*)(ws + 6553600);             //  1,966,080 B
        u32*      H6P = (u32*)(ws + 8519680);             //  1,376,256 B
        for (int c = 0; c < 2; ++c) {
            k_tr  <<<dim3(128, 16), 256, 0, stream>>>(x + (size_t)c * 8192 * 1024, XP);
            k_c1s2<<<dim3(32, 42), 256, 0, stream>>>(XP, w1, b1, s2w, s2b, S2P, 8192);
            k_c3s4<<<dim3(32, 80), 256, 0, stream>>>(S2P, w3, b3, s4w, s4b, S4H, 8192);
            k_c5  <<<dim3(32, 12), 256, 0, stream>>>(S4H, w5, b5, H5P, 8192);
            k_f6  <<<dim3(32, 6), 256, 0, stream>>>(H5P, f6w, f6b, H6P, 8192);
            k_rbf <<<dim3(32, 5), 256, 0, stream>>>(H6P, rbfw, out + (size_t)c * 8192 * 10, 8192);
        }
    }
}